// Round 15
// baseline (228.516 us; speedup 1.0000x reference)
//
#include <hip/hip_runtime.h>
#include <math.h>

#define EPS 1e-5f

// L=4, B=16, N=8, P=64, D=128, F=128, H=8
// M = B*N*P = 8192 rows, HF = 1024, QKV width = 3072

typedef __bf16 bf16x8 __attribute__((ext_vector_type(8)));
typedef __bf16 bf16x4 __attribute__((ext_vector_type(4)));
typedef float f32x4 __attribute__((ext_vector_type(4)));

#define MFMA16 __builtin_amdgcn_mfma_f32_16x16x32_bf16

__device__ __forceinline__ float gelu_f(float x) {
    return 0.5f * x * (1.0f + erff(x * 0.7071067811865476f));
}

// async 16B global->LDS (linear dest, per-lane source)
__device__ __forceinline__ void gll16(const void* g, void* l) {
    __builtin_amdgcn_global_load_lds(
        (const __attribute__((address_space(1))) void*)g,
        (__attribute__((address_space(3))) void*)l, 16, 0, 0);
}

__device__ __forceinline__ void cvt_store8(void* dst, const float* __restrict__ src) {
    float4 a = ((const float4*)src)[0];
    float4 b = ((const float4*)src)[1];
    bf16x8 v;
    v[0] = (__bf16)a.x; v[1] = (__bf16)a.y; v[2] = (__bf16)a.z; v[3] = (__bf16)a.w;
    v[4] = (__bf16)b.x; v[5] = (__bf16)b.y; v[6] = (__bf16)b.z; v[7] = (__bf16)b.w;
    *(bf16x8*)dst = v;
}

// XOR swizzles (period-8 row stripe, 16B granules)
__device__ __forceinline__ int swz(int row, int k0)   { return row * 128 + (k0 ^ ((row & 7) << 3)); }
__device__ __forceinline__ int swz64(int row, int k0) { return row * 64  + (k0 ^ ((row & 7) << 3)); }

// ---------------------------------------------------------------------------
// Prep (merged): blocks [0,1536): blend-folded QKV weight (per-head layout
// Wq[l][h*384+type*128+f][256]) + bias.  Blocks [1536,2192): f32->bf16 cvt.
// ---------------------------------------------------------------------------
__global__ __launch_bounds__(256) void prep_all(
    const float* __restrict__ Wc, const float* __restrict__ bc,
    const float* __restrict__ Wpq, const float* __restrict__ bp,
    const float* __restrict__ alpha,
    __bf16* __restrict__ Wq, float* __restrict__ bq,
    const float* __restrict__ s0, __bf16* __restrict__ d0, int n0,
    const float* __restrict__ s1, __bf16* __restrict__ d1, int n1,
    const float* __restrict__ s2, __bf16* __restrict__ d2, int n2,
    const float* __restrict__ s3, __bf16* __restrict__ d3, int n3)
{
    int b = blockIdx.x;
    if (b < 1536) {
        int idx = b * 256 + threadIdx.x;               // [0, 393216)
        int l = idx / 98304, rem = idx - l * 98304;    // 98304 = 3072*32
        int row = rem >> 5, g = rem & 31, k0 = g << 3; // row: type*1024+h*128+f
        int type = row >> 10, hf = row & 1023, h = hf >> 7, f = hf & 127;
        int rowp = h * 384 + type * 128 + f;
        float a = 1.0f / (1.0f + expf(-alpha[l * 3072 + row]));
        __bf16* dst = Wq + ((size_t)l * 3072 + rowp) * 256 + k0;
        if (k0 < 128) {
            const float* s = Wc + ((size_t)l * 3072 + row) * 128 + k0;
#pragma unroll
            for (int j = 0; j < 8; ++j) dst[j] = (__bf16)(a * s[j]);
        } else {
            const float* s = Wpq + ((size_t)l * 3072 + row) * 128 + (k0 - 128);
#pragma unroll
            for (int j = 0; j < 8; ++j) dst[j] = (__bf16)((1.0f - a) * s[j]);
        }
        if (g == 0)
            bq[l * 3072 + rowp] = a * bc[l * 3072 + row] + (1.0f - a) * bp[l * 3072 + row];
    } else {
        int off = ((b - 1536) * 256 + threadIdx.x) * 4;
        const float* s; __bf16* d;
        if (off < n0) { s = s0; d = d0; }
        else {
            off -= n0;
            if (off < n1) { s = s1; d = d1; }
            else {
                off -= n1;
                if (off < n2) { s = s2; d = d2; }
                else {
                    off -= n2;
                    if (off >= n3) return;
                    s = s3; d = d3;
                }
            }
        }
        float4 v = *(const float4*)(s + off);
        d[off] = (__bf16)v.x; d[off + 1] = (__bf16)v.y;
        d[off + 2] = (__bf16)v.z; d[off + 3] = (__bf16)v.w;
    }
}

// ---------------------------------------------------------------------------
// Kernel 1 (merged lin): 64-row tiles.
// blocks [0,512): pre[l] = LN(Hpre[l] @ pro2[l]^T + b)   (l = b>>7)
// blocks [512,640): cur  = LN(seq @ pro1^T + b) -> f32 cur + bf16 Xc
// ---------------------------------------------------------------------------
__global__ __launch_bounds__(256) void lin_all(
    const float* __restrict__ Hpre, const __bf16* __restrict__ pro2b,
    const float* __restrict__ pro2bias,
    const float* __restrict__ lnps, const float* __restrict__ lnpb,
    __bf16* __restrict__ preb,
    const float* __restrict__ seq, const __bf16* __restrict__ pro1b,
    const float* __restrict__ pro1bias,
    const float* __restrict__ lncs, const float* __restrict__ lncb,
    float* __restrict__ curf, __bf16* __restrict__ Xcb)
{
    __shared__ __align__(16) char lds[49152];
    unsigned short* xs = (unsigned short*)lds;            // [64][128] 16KB
    unsigned short* ws = (unsigned short*)(lds + 16384);  // [128][128] 32KB
    float* outs = (float*)lds;                            // [64][132] alias
    int b = blockIdx.x, t = threadIdx.x;
    const float* x; const __bf16* W; const float* bias;
    const float* lns; const float* lnb;
    float* yf = nullptr; __bf16* Xout; int R;
    if (b < 512) {
        int l = b >> 7; R = (b & 127) * 64;
        x = Hpre + (size_t)l * 8192 * 128;
        W = pro2b + (size_t)l * 16384;
        bias = pro2bias + l * 128; lns = lnps + l * 128; lnb = lnpb + l * 128;
        Xout = preb + (size_t)l * 8192 * 128;
    } else {
        R = (b - 512) * 64;
        x = seq; W = pro1b; bias = pro1bias; lns = lncs; lnb = lncb;
        yf = curf; Xout = Xcb;
    }
#pragma unroll
    for (int i = 0; i < 4; ++i) {
        int c = t + i * 256; int row = c >> 4, k0 = (c & 15) << 3;
        cvt_store8(&xs[swz(row, k0)], x + (size_t)(R + row) * 128 + k0);
    }
#pragma unroll
    for (int i = 0; i < 8; ++i) {
        int c = t + i * 256; int row = c >> 4, k0 = (c & 15) << 3;
        gll16(W + (size_t)row * 128 + (k0 ^ ((row & 7) << 3)), &ws[c * 8]);
    }
    __syncthreads();
    int lane = t & 63, w = t >> 6;
    int wr = w * 16;
    int fr = lane & 15, fk = (lane >> 4) << 3;
    f32x4 acc[8] = {};
#pragma unroll
    for (int kk = 0; kk < 4; ++kk) {
        int k0 = kk * 32 + fk;
        bf16x8 a = *(const bf16x8*)&xs[swz(wr + fr, k0)];
#pragma unroll
        for (int n = 0; n < 8; ++n) {
            bf16x8 bb = *(const bf16x8*)&ws[swz(n * 16 + fr, k0)];
            acc[n] = MFMA16(a, bb, acc[n], 0, 0, 0);
        }
    }
    __syncthreads();
#pragma unroll
    for (int n = 0; n < 8; ++n) {
        int col = n * 16 + fr;
        float bv = bias[col];
        int rl = wr + ((lane >> 4) << 2);
#pragma unroll
        for (int r = 0; r < 4; ++r) outs[(rl + r) * 132 + col] = acc[n][r] + bv;
    }
    __syncthreads();
    int row = t >> 2, oc = t & 3;
    float vals[32]; float s = 0.0f;
#pragma unroll
    for (int i = 0; i < 32; ++i) { vals[i] = outs[row * 132 + oc + 4 * i]; s += vals[i]; }
    s += __shfl_xor(s, 1, 4); s += __shfl_xor(s, 2, 4);
    float mean = s * (1.0f / 128.0f);
    float sq = 0.0f;
#pragma unroll
    for (int i = 0; i < 32; ++i) { float d = vals[i] - mean; sq += d * d; }
    sq += __shfl_xor(sq, 1, 4); sq += __shfl_xor(sq, 2, 4);
    float rs = rsqrtf(sq * (1.0f / 128.0f) + EPS);
#pragma unroll
    for (int i = 0; i < 32; ++i) {
        int c = oc + 4 * i;
        float yv = (vals[i] - mean) * rs * lns[c] + lnb[c];
        if (yf) yf[(size_t)(R + row) * 128 + c] = yv;
        Xout[(size_t)(R + row) * 128 + c] = (__bf16)yv;
    }
}

// ---------------------------------------------------------------------------
// Kernel 2 (fused): per (bn,h): QKV GEMM (64x384, K=256) -> QK^T -> softmax
// -> PV -> bn1 LN -> At (coalesced via LDS bounce).
// Phase 1 uses wave-private DOUBLE-BUFFERED slabs [96][32] (6KB x2 per wave)
// with counted vmcnt(6) -> weight loads never drain (T4 pipeline).
// ---------------------------------------------------------------------------
__global__ __launch_bounds__(256, 2) void qkv_attn(
    const __bf16* __restrict__ Xc, const __bf16* __restrict__ Pre,
    const __bf16* __restrict__ Wq, const float* __restrict__ bq,
    const float* __restrict__ bn1s, const float* __restrict__ bn1b,
    __bf16* __restrict__ At)
{
    __shared__ __align__(16) char lds[81920];
    unsigned short* Xs = (unsigned short*)lds;   // [64][256] 32KB
    __bf16* Qs  = (__bf16*)lds;             // [64][128] 16KB (phase 2/3 alias)
    __bf16* Ks  = (__bf16*)(lds + 16384);   // [64][128] 16KB
    __bf16* Vts = (__bf16*)(lds + 32768);   // [128][64] 16KB
    __bf16* Ps  = (__bf16*)lds;             // [64][64]  8KB, aliases Qs
    __bf16* Os  = (__bf16*)(lds + 49152);   // [64][136] 17KB, free in phase 3

    int bn = blockIdx.x >> 3, h = blockIdx.x & 7;
    int t = threadIdx.x, lane = t & 63, w = t >> 6;
    int fr = lane & 15, fk = (lane >> 4) << 3;
    int rr = (lane >> 4) << 2;
    int w16 = w * 16;
    const __bf16* Wqh = Wq + (size_t)h * 384 * 256;
    const float* bqh = bq + h * 384;
    // two wave-private slab buffers, [96][32] bf16 each (6KB)
    unsigned short* slabs = (unsigned short*)(lds + 32768 + w * 12288);

    // ---- stage Xs (all threads) + slab batches 0,1; one barrier (drains all)
#pragma unroll
    for (int i = 0; i < 8; ++i) {
        int c = t + i * 256;                // [0,2048) 16B chunks
        int row = c >> 5, k0 = (c & 31) << 3;
        int ks = k0 ^ ((row & 7) << 3);
        const __bf16* src = (ks < 128)
            ? Xc + (size_t)(bn * 64 + row) * 128 + ks
            : Pre + (size_t)(bn * 64 + row) * 128 + (ks - 128);
        gll16(src, &Xs[c * 8]);
    }
#pragma unroll
    for (int kb = 0; kb < 2; ++kb) {
        unsigned short* sb = slabs + kb * 3072;
#pragma unroll
        for (int i = 0; i < 6; ++i) {
            int c = lane + i * 64;          // [0,384): rl = c>>2, k0 = (c&3)<<3
            int rl = c >> 2, k0 = (c & 3) << 3;
            gll16(Wqh + (size_t)(w * 96 + rl) * 256 + kb * 32 + (k0 ^ ((rl & 3) << 3)),
                  &sb[c * 8]);
        }
    }
    __syncthreads();                        // B0: Xs + batches 0,1 visible (vmcnt drained)

    // ---- phase 1: counted-vmcnt pipelined K-loop (8 chunks of K=32)
    f32x4 acc[4][6] = {};
    for (int kc = 0; kc < 8; ++kc) {
        if (kc < 7) asm volatile("s_waitcnt vmcnt(6)" ::: "memory");
        else        asm volatile("s_waitcnt vmcnt(0)" ::: "memory");
        __builtin_amdgcn_sched_barrier(0);
        unsigned short* sb = slabs + (kc & 1) * 3072;
        int kg = kc * 32 + fk;              // k within 256 (Xs)
        bf16x8 a[4], b[6];
#pragma unroll
        for (int m = 0; m < 4; ++m) {
            int row = m * 16 + fr;
            a[m] = *(const bf16x8*)&Xs[row * 256 + (kg ^ ((row & 7) << 3))];
        }
#pragma unroll
        for (int n = 0; n < 6; ++n) {
            int rl = n * 16 + fr;
            b[n] = *(const bf16x8*)&sb[rl * 32 + (fk ^ ((rl & 3) << 3))];
        }
        asm volatile("s_waitcnt lgkmcnt(0)" ::: "memory");  // frags in regs
        __builtin_amdgcn_sched_barrier(0);
        if (kc + 2 < 8) {                   // refill the buffer just consumed
#pragma unroll
            for (int i = 0; i < 6; ++i) {
                int c = lane + i * 64;
                int rl = c >> 2, k0 = (c & 3) << 3;
                gll16(Wqh + (size_t)(w * 96 + rl) * 256 + (kc + 2) * 32 +
                          (k0 ^ ((rl & 3) << 3)),
                      &sb[c * 8]);
            }
        }
#pragma unroll
        for (int m = 0; m < 4; ++m)
#pragma unroll
            for (int n = 0; n < 6; ++n)
                acc[m][n] = MFMA16(a[m], b[n], acc[m][n], 0, 0, 0);
    }
    __syncthreads();                        // B1: all slab/Xs reads done

    // ---- phase 2: +bias, scatter to Q/K/V LDS (bf16, swizzled)
#pragma unroll
    for (int n = 0; n < 6; ++n) {
        int colb = w * 96 + n * 16;
        int type = colb >> 7;                    // wave-uniform
        float bv = bqh[colb + fr];
        int f = (colb & 127) + fr;
#pragma unroll
        for (int m = 0; m < 4; ++m) {
            if (type == 2) {                     // V^T: 4 consecutive rows pack
                int rbase = m * 16 + rr;
                bf16x4 pk;
#pragma unroll
                for (int r = 0; r < 4; ++r) pk[r] = (__bf16)(acc[m][n][r] + bv);
                *(bf16x4*)&Vts[f * 64 + (rbase ^ ((f & 7) << 3))] = pk;
            } else {
#pragma unroll
                for (int r = 0; r < 4; ++r) {
                    int row = m * 16 + rr + r;
                    float val = acc[m][n][r] + bv;
                    if (type == 0)
                        Qs[row * 128 + (f ^ ((row & 7) << 3))] = (__bf16)val;
                    else
                        Ks[row * 128 + (f ^ ((row & 7) << 3))] = (__bf16)val;
                }
            }
        }
    }
    __syncthreads();                        // B2: Q/K/V ready

    // ---- phase 3a: QK^T rows [w16,+16) x 64 cols (Q rows are wave-local)
    f32x4 sacc[4] = {};
#pragma unroll
    for (int kk = 0; kk < 4; ++kk) {
        int k0 = kk * 32 + fk;
        int arow = w16 + fr;
        bf16x8 aq = *(const bf16x8*)&Qs[arow * 128 + (k0 ^ ((arow & 7) << 3))];
#pragma unroll
        for (int n = 0; n < 4; ++n) {
            bf16x8 bk = *(const bf16x8*)&Ks[swz(n * 16 + fr, k0)];
            sacc[n] = MFMA16(aq, bk, sacc[n], 0, 0, 0);
        }
    }
    __syncthreads();                        // B3: Qs dead -> Ps writes may alias

    // ---- phase 3b: softmax -> Ps (wave-local rows; no barrier before PV)
    const float scale = 0.08838834764831845f;   // 128^-0.5
#pragma unroll
    for (int r = 0; r < 4; ++r) {
        float sv[4];
#pragma unroll
        for (int n = 0; n < 4; ++n) sv[n] = sacc[n][r] * scale;
        float mx = fmaxf(fmaxf(sv[0], sv[1]), fmaxf(sv[2], sv[3]));
        mx = fmaxf(mx, __shfl_xor(mx, 1, 16));
        mx = fmaxf(mx, __shfl_xor(mx, 2, 16));
        mx = fmaxf(mx, __shfl_xor(mx, 4, 16));
        mx = fmaxf(mx, __shfl_xor(mx, 8, 16));
        float sum = 0.0f;
#pragma unroll
        for (int n = 0; n < 4; ++n) { sv[n] = expf(sv[n] - mx); sum += sv[n]; }
        sum += __shfl_xor(sum, 1, 16);
        sum += __shfl_xor(sum, 2, 16);
        sum += __shfl_xor(sum, 4, 16);
        sum += __shfl_xor(sum, 8, 16);
        float inv = 1.0f / sum;
        int p = w16 + rr + r;
#pragma unroll
        for (int n = 0; n < 4; ++n) {
            int q = n * 16 + fr;
            Ps[p * 64 + (q ^ ((p & 7) << 3))] = (__bf16)(sv[n] * inv);
        }
    }
    // PV reads only this wave's Ps rows -> wave-internal lgkmcnt ordering.

    // ---- phase 3c: PV rows [w16,+16) x 128 f
    f32x4 oacc[8] = {};
#pragma unroll
    for (int kk = 0; kk < 2; ++kk) {
        int k0 = kk * 32 + fk;
        int arow = w16 + fr;
        bf16x8 ap = *(const bf16x8*)&Ps[arow * 64 + (k0 ^ ((arow & 7) << 3))];
#pragma unroll
        for (int n = 0; n < 8; ++n) {
            bf16x8 bv = *(const bf16x8*)&Vts[swz64(n * 16 + fr, k0)];
            oacc[n] = MFMA16(ap, bv, oacc[n], 0, 0, 0);
        }
    }

    // ---- bn1 LN over f(128) -> Os (LDS bounce, wave-local rows)
#pragma unroll
    for (int r = 0; r < 4; ++r) {
        int p = w16 + rr + r;
        float s1 = 0.0f;
#pragma unroll
        for (int n = 0; n < 8; ++n) s1 += oacc[n][r];
        s1 += __shfl_xor(s1, 1, 16);
        s1 += __shfl_xor(s1, 2, 16);
        s1 += __shfl_xor(s1, 4, 16);
        s1 += __shfl_xor(s1, 8, 16);
        float mean = s1 * (1.0f / 128.0f);
        float s2 = 0.0f;
#pragma unroll
        for (int n = 0; n < 8; ++n) { float d = oacc[n][r] - mean; s2 += d * d; }
        s2 += __shfl_xor(s2, 1, 16);
        s2 += __shfl_xor(s2, 2, 16);
        s2 += __shfl_xor(s2, 4, 16);
        s2 += __shfl_xor(s2, 8, 16);
        float rs = rsqrtf(s2 * (1.0f / 128.0f) + EPS);
#pragma unroll
        for (int n = 0; n < 8; ++n) {
            int f = n * 16 + fr;
            Os[p * 136 + f] = (__bf16)((oacc[n][r] - mean) * rs * bn1s[f] + bn1b[f]);
        }
    }
    // order own-wave ds_writes before the readback ds_reads (rule #18)
    asm volatile("s_waitcnt lgkmcnt(0)" ::: "memory");
    __builtin_amdgcn_sched_barrier(0);

    // ---- coalesced At write: wave reads back its 16 rows lane-linearly
#pragma unroll
    for (int i = 0; i < 4; ++i) {
        int c = lane + i * 64;              // [0,256): 16 rows x 16 chunks
        int rl = c >> 4, ch = c & 15;
        int row = w16 + rl;
        bf16x8 v = *(const bf16x8*)&Os[row * 136 + ch * 8];
        *(bf16x8*)(At + (size_t)(bn * 64 + row) * 1024 + h * 128 + ch * 8) = v;
    }
}

// ---------------------------------------------------------------------------
// Kernel 3 (MFMA): proj (K=1024) + bn2 LN + gelu(cur) residual + ln_o LN
// + ffn GEMM + gelu(O_hat).  16-row tile, grid 512 -> 2 blocks/CU.
// ---------------------------------------------------------------------------
__global__ __launch_bounds__(256) void proj_ffn_mfma(
    const __bf16* __restrict__ At_g, const __bf16* __restrict__ Wp,
    const float* __restrict__ pb,
    const float* __restrict__ bn2s, const float* __restrict__ bn2b,
    const float* __restrict__ lnos, const float* __restrict__ lnob,
    const __bf16* __restrict__ Wf, const float* __restrict__ fb,
    const float* __restrict__ cur, float* __restrict__ out,
    __bf16* __restrict__ Xcur)
{
    __shared__ __align__(16) char lds[36864];
    unsigned short* ats = (unsigned short*)lds;           // [16][128] bf16 4KB
    unsigned short* wts = (unsigned short*)(lds + 4096);  // [128][128] bf16 32KB
    float* outs = (float*)lds;                            // [16][132] f32 alias
    int t = threadIdx.x;
    int R = blockIdx.x * 16;
    int lane = t & 63, w = t >> 6;
    int wcol = w * 32;
    int fr = lane & 15, fk = (lane >> 4) << 3;
    int rr = (lane >> 4) << 2;

    f32x4 acc[2] = {};
    for (int kc = 0; kc < 8; ++kc) {
        {
            int row = t >> 4, k0 = (t & 15) << 3;
            gll16(At_g + (size_t)(R + row) * 1024 + kc * 128 + (k0 ^ ((row & 7) << 3)),
                  &ats[t * 8]);
        }
#pragma unroll
        for (int i = 0; i < 8; ++i) {
            int c = t + i * 256; int row = c >> 4, k0 = (c & 15) << 3;
            gll16(Wp + (size_t)row * 1024 + kc * 128 + (k0 ^ ((row & 7) << 3)),
                  &wts[c * 8]);
        }
        __syncthreads();
#pragma unroll
        for (int kk = 0; kk < 4; ++kk) {
            int k0 = kk * 32 + fk;
            bf16x8 a = *(const bf16x8*)&ats[swz(fr, k0)];
#pragma unroll
            for (int n = 0; n < 2; ++n) {
                bf16x8 b = *(const bf16x8*)&wts[swz(wcol + n * 16 + fr, k0)];
                acc[n] = MFMA16(a, b, acc[n], 0, 0, 0);
            }
        }
        __syncthreads();
    }

#pragma unroll
    for (int n = 0; n < 2; ++n) {
        int col = wcol + n * 16 + fr;
        float bv = pb[col];
#pragma unroll
        for (int r = 0; r < 4; ++r) outs[(rr + r) * 132 + col] = acc[n][r] + bv;
    }
    __syncthreads();

    int row = t >> 4, oc = t & 15;
    float vals[8]; float s = 0.0f;
#pragma unroll
    for (int i = 0; i < 8; ++i) { vals[i] = outs[row * 132 + oc + 16 * i]; s += vals[i]; }
    s += __shfl_xor(s, 1, 16); s += __shfl_xor(s, 2, 16);
    s += __shfl_xor(s, 4, 16); s += __shfl_xor(s, 8, 16);
    float mean = s * (1.0f / 128.0f);
    float sq = 0.0f;
#pragma unroll
    for (int i = 0; i < 8; ++i) { float d = vals[i] - mean; sq += d * d; }
    sq += __shfl_xor(sq, 1, 16); sq += __shfl_xor(sq, 2, 16);
    sq += __shfl_xor(sq, 4, 16); sq += __shfl_xor(sq, 8, 16);
    float rs = rsqrtf(sq * (1.0f / 128.0f) + EPS);

    float oh[8]; float s2 = 0.0f;
#pragma unroll
    for (int i = 0; i < 8; ++i) {
        int c = oc + 16 * i;
        float ynorm = (vals[i] - mean) * rs * bn2s[c] + bn2b[c];
        float cv = cur[(size_t)(R + row) * 128 + c];
        oh[i] = cv + (ynorm + gelu_f(cv));
        s2 += oh[i];
    }
    s2 += __shfl_xor(s2, 1, 16); s2 += __shfl_xor(s2, 2, 16);
    s2 += __shfl_xor(s2, 4, 16); s2 += __shfl_xor(s2, 8, 16);
    float mean2 = s2 * (1.0f / 128.0f);
    float sq2 = 0.0f;
#pragma unroll
    for (int i = 0; i < 8; ++i) { float d = oh[i] - mean2; sq2 += d * d; }
    sq2 += __shfl_xor(sq2, 1, 16); sq2 += __shfl_xor(sq2, 2, 16);
    sq2 += __shfl_xor(sq2, 4, 16); sq2 += __shfl_xor(sq2, 8, 16);
    float rs2 = rsqrtf(sq2 * (1.0f / 128.0f) + EPS);
#pragma unroll
    for (int i = 0; i < 8; ++i) {
        int c = oc + 16 * i;
        oh[i] = (oh[i] - mean2) * rs2 * lnos[c] + lnob[c];   // O_hat
    }
    __syncthreads();

#pragma unroll
    for (int i = 0; i < 8; ++i) {
        int c = oc + 16 * i;
        ((__bf16*)ats)[row * 128 + (c ^ ((row & 7) << 3))] = (__bf16)oh[i];
    }
#pragma unroll
    for (int i = 0; i < 8; ++i) {
        int c = t + i * 256; int rw = c >> 4, k0 = (c & 15) << 3;
        gll16(Wf + (size_t)rw * 128 + (k0 ^ ((rw & 7) << 3)), &wts[c * 8]);
    }
    __syncthreads();

    f32x4 acc2[2] = {};
#pragma unroll
    for (int kk = 0; kk < 4; ++kk) {
        int k0 = kk * 32 + fk;
        bf16x8 a = *(const bf16x8*)&ats[swz(fr, k0)];
#pragma unroll
        for (int n = 0; n < 2; ++n) {
            bf16x8 b = *(const bf16x8*)&wts[swz(wcol + n * 16 + fr, k0)];
            acc2[n] = MFMA16(a, b, acc2[n], 0, 0, 0);
        }
    }
#pragma unroll
    for (int n = 0; n < 2; ++n) {
        int col = wcol + n * 16 + fr;
        float bv = fb[col];
#pragma unroll
        for (int r = 0; r < 4; ++r) {
            int ro = rr + r;
            float ov = (float)((__bf16*)ats)[ro * 128 + (col ^ ((ro & 7) << 3))];
            float val = acc2[n][r] + bv + gelu_f(ov);
            size_t gidx = (size_t)(R + ro) * 128 + col;
            out[gidx] = val;
            if (Xcur) Xcur[gidx] = (__bf16)val;
        }
    }
}

// ---------------------------------------------------------------------------
extern "C" void kernel_launch(void* const* d_in, const int* in_sizes, int n_in,
                              void* d_out, int out_size, void* d_ws, size_t ws_size,
                              hipStream_t stream)
{
    const float* seq       = (const float*)d_in[0];
    const float* Hpre      = (const float*)d_in[1];
    const float* pro1_w    = (const float*)d_in[2];
    const float* pro1_b    = (const float*)d_in[3];
    const float* pro2_w    = (const float*)d_in[4];
    const float* pro2_b    = (const float*)d_in[5];
    const float* ln_cur_s  = (const float*)d_in[6];
    const float* ln_cur_b  = (const float*)d_in[7];
    const float* ln_pre_s  = (const float*)d_in[8];
    const float* ln_pre_b  = (const float*)d_in[9];
    const float* cur_qkv_w = (const float*)d_in[10];
    const float* cur_qkv_b = (const float*)d_in[11];
    const float* pre_qkv_w = (const float*)d_in[12];
    const float* pre_qkv_b = (const float*)d_in[13];
    const float* alpha     = (const float*)d_in[14];
    const float* proj_w    = (const float*)d_in[15];
    const float* proj_b    = (const float*)d_in[16];
    const float* bn1_s     = (const float*)d_in[17];
    const float* bn1_b     = (const float*)d_in[18];
    const float* bn2_s     = (const float*)d_in[19];
    const float* bn2_b     = (const float*)d_in[20];
    const float* ln_o_s    = (const float*)d_in[21];
    const float* ln_o_b    = (const float*)d_in[22];
    const float* ffn_w     = (const float*)d_in[23];
    const float* ffn_b     = (const float*)d_in[24];

    char* ws = (char*)d_ws;
    __bf16* Wq      = (__bf16*)ws;                 ws += (size_t)4 * 3072 * 256 * 2;
    float*  bq      = (float*)ws;                  ws += (size_t)4 * 3072 * 4;
    __bf16* Wp_bf   = (__bf16*)ws;                 ws += (size_t)4 * 128 * 1024 * 2;
    __bf16* Wf_bf   = (__bf16*)ws;                 ws += (size_t)4 * 128 * 128 * 2;
    __bf16* pro1_bf = (__bf16*)ws;                 ws += (size_t)128 * 128 * 2;
    __bf16* pro2_bf = (__bf16*)ws;                 ws += (size_t)4 * 128 * 128 * 2;
    __bf16* Xc   = (__bf16*)ws;                    ws += (size_t)8192 * 128 * 2;
    __bf16* preb = (__bf16*)ws;                    ws += (size_t)4 * 8192 * 128 * 2;
    float*  cur  = (float*)ws;                     ws += (size_t)8192 * 128 * 4;
    __bf16* Atb  = (__bf16*)ws;                    ws += (size_t)8192 * 1024 * 2;

    prep_all<<<2192, 256, 0, stream>>>(
        cur_qkv_w, cur_qkv_b, pre_qkv_w, pre_qkv_b, alpha, Wq, bq,
        proj_w, Wp_bf, 4 * 128 * 1024,
        ffn_w, Wf_bf, 4 * 128 * 128,
        pro1_w, pro1_bf, 128 * 128,
        pro2_w, pro2_bf, 4 * 128 * 128);
    lin_all<<<640, 256, 0, stream>>>(Hpre, pro2_bf, pro2_b, ln_pre_s, ln_pre_b,
                                     preb, seq, pro1_bf, pro1_b,
                                     ln_cur_s, ln_cur_b, cur, Xc);

    for (int l = 0; l < 4; ++l) {
        qkv_attn<<<1024, 256, 0, stream>>>(
            Xc, preb + (size_t)l * 8192 * 128,
            Wq + (size_t)l * 3072 * 256, bq + l * 3072,
            bn1_s + l * 128, bn1_b + l * 128, Atb);
        float* outp = (l == 3) ? (float*)d_out : cur;
        proj_ffn_mfma<<<512, 256, 0, stream>>>(Atb,
                                               Wp_bf + (size_t)l * 128 * 1024,
                                               proj_b + l * 128,
                                               bn2_s + l * 128, bn2_b + l * 128,
                                               ln_o_s + l * 128, ln_o_b + l * 128,
                                               Wf_bf + (size_t)l * 16384,
                                               ffn_b + l * 128,
                                               cur, outp, (l == 3) ? nullptr : Xc);
    }
}

// Round 16
// 221.255 us; speedup vs baseline: 1.0328x; 1.0328x over previous
//
#include <hip/hip_runtime.h>
#include <math.h>

#define EPS 1e-5f

// L=4, B=16, N=8, P=64, D=128, F=128, H=8
// M = B*N*P = 8192 rows, HF = 1024, QKV width = 3072

typedef __bf16 bf16x8 __attribute__((ext_vector_type(8)));
typedef __bf16 bf16x4 __attribute__((ext_vector_type(4)));
typedef float f32x4 __attribute__((ext_vector_type(4)));

#define MFMA16 __builtin_amdgcn_mfma_f32_16x16x32_bf16

__device__ __forceinline__ float gelu_f(float x) {
    return 0.5f * x * (1.0f + erff(x * 0.7071067811865476f));
}

// async 16B global->LDS (linear dest, per-lane source)
__device__ __forceinline__ void gll16(const void* g, void* l) {
    __builtin_amdgcn_global_load_lds(
        (const __attribute__((address_space(1))) void*)g,
        (__attribute__((address_space(3))) void*)l, 16, 0, 0);
}

__device__ __forceinline__ void cvt_store8(void* dst, const float* __restrict__ src) {
    float4 a = ((const float4*)src)[0];
    float4 b = ((const float4*)src)[1];
    bf16x8 v;
    v[0] = (__bf16)a.x; v[1] = (__bf16)a.y; v[2] = (__bf16)a.z; v[3] = (__bf16)a.w;
    v[4] = (__bf16)b.x; v[5] = (__bf16)b.y; v[6] = (__bf16)b.z; v[7] = (__bf16)b.w;
    *(bf16x8*)dst = v;
}

// XOR swizzles (period-8 row stripe, 16B granules)
__device__ __forceinline__ int swz(int row, int k0)   { return row * 128 + (k0 ^ ((row & 7) << 3)); }
__device__ __forceinline__ int swz64(int row, int k0) { return row * 64  + (k0 ^ ((row & 7) << 3)); }

// ---------------------------------------------------------------------------
// Prep (merged): blocks [0,1536): blend-folded QKV weight (per-head layout
// Wq[l][h*384+type*128+f][256]) + bias.  Blocks [1536,2192): f32->bf16 cvt.
// ---------------------------------------------------------------------------
__global__ __launch_bounds__(256) void prep_all(
    const float* __restrict__ Wc, const float* __restrict__ bc,
    const float* __restrict__ Wpq, const float* __restrict__ bp,
    const float* __restrict__ alpha,
    __bf16* __restrict__ Wq, float* __restrict__ bq,
    const float* __restrict__ s0, __bf16* __restrict__ d0, int n0,
    const float* __restrict__ s1, __bf16* __restrict__ d1, int n1,
    const float* __restrict__ s2, __bf16* __restrict__ d2, int n2,
    const float* __restrict__ s3, __bf16* __restrict__ d3, int n3)
{
    int b = blockIdx.x;
    if (b < 1536) {
        int idx = b * 256 + threadIdx.x;               // [0, 393216)
        int l = idx / 98304, rem = idx - l * 98304;    // 98304 = 3072*32
        int row = rem >> 5, g = rem & 31, k0 = g << 3; // row: type*1024+h*128+f
        int type = row >> 10, hf = row & 1023, h = hf >> 7, f = hf & 127;
        int rowp = h * 384 + type * 128 + f;
        float a = 1.0f / (1.0f + expf(-alpha[l * 3072 + row]));
        __bf16* dst = Wq + ((size_t)l * 3072 + rowp) * 256 + k0;
        if (k0 < 128) {
            const float* s = Wc + ((size_t)l * 3072 + row) * 128 + k0;
#pragma unroll
            for (int j = 0; j < 8; ++j) dst[j] = (__bf16)(a * s[j]);
        } else {
            const float* s = Wpq + ((size_t)l * 3072 + row) * 128 + (k0 - 128);
#pragma unroll
            for (int j = 0; j < 8; ++j) dst[j] = (__bf16)((1.0f - a) * s[j]);
        }
        if (g == 0)
            bq[l * 3072 + rowp] = a * bc[l * 3072 + row] + (1.0f - a) * bp[l * 3072 + row];
    } else {
        int off = ((b - 1536) * 256 + threadIdx.x) * 4;
        const float* s; __bf16* d;
        if (off < n0) { s = s0; d = d0; }
        else {
            off -= n0;
            if (off < n1) { s = s1; d = d1; }
            else {
                off -= n1;
                if (off < n2) { s = s2; d = d2; }
                else {
                    off -= n2;
                    if (off >= n3) return;
                    s = s3; d = d3;
                }
            }
        }
        float4 v = *(const float4*)(s + off);
        d[off] = (__bf16)v.x; d[off + 1] = (__bf16)v.y;
        d[off + 2] = (__bf16)v.z; d[off + 3] = (__bf16)v.w;
    }
}

// ---------------------------------------------------------------------------
// Kernel 1 (merged lin): 64-row tiles.
// blocks [0,512): pre[l] = LN(Hpre[l] @ pro2[l]^T + b)   (l = b>>7)
// blocks [512,640): cur  = LN(seq @ pro1^T + b) -> f32 cur + bf16 Xc
// ---------------------------------------------------------------------------
__global__ __launch_bounds__(256) void lin_all(
    const float* __restrict__ Hpre, const __bf16* __restrict__ pro2b,
    const float* __restrict__ pro2bias,
    const float* __restrict__ lnps, const float* __restrict__ lnpb,
    __bf16* __restrict__ preb,
    const float* __restrict__ seq, const __bf16* __restrict__ pro1b,
    const float* __restrict__ pro1bias,
    const float* __restrict__ lncs, const float* __restrict__ lncb,
    float* __restrict__ curf, __bf16* __restrict__ Xcb)
{
    __shared__ __align__(16) char lds[49152];
    unsigned short* xs = (unsigned short*)lds;            // [64][128] 16KB
    unsigned short* ws = (unsigned short*)(lds + 16384);  // [128][128] 32KB
    float* outs = (float*)lds;                            // [64][132] alias
    int b = blockIdx.x, t = threadIdx.x;
    const float* x; const __bf16* W; const float* bias;
    const float* lns; const float* lnb;
    float* yf = nullptr; __bf16* Xout; int R;
    if (b < 512) {
        int l = b >> 7; R = (b & 127) * 64;
        x = Hpre + (size_t)l * 8192 * 128;
        W = pro2b + (size_t)l * 16384;
        bias = pro2bias + l * 128; lns = lnps + l * 128; lnb = lnpb + l * 128;
        Xout = preb + (size_t)l * 8192 * 128;
    } else {
        R = (b - 512) * 64;
        x = seq; W = pro1b; bias = pro1bias; lns = lncs; lnb = lncb;
        yf = curf; Xout = Xcb;
    }
#pragma unroll
    for (int i = 0; i < 4; ++i) {
        int c = t + i * 256; int row = c >> 4, k0 = (c & 15) << 3;
        cvt_store8(&xs[swz(row, k0)], x + (size_t)(R + row) * 128 + k0);
    }
#pragma unroll
    for (int i = 0; i < 8; ++i) {
        int c = t + i * 256; int row = c >> 4, k0 = (c & 15) << 3;
        gll16(W + (size_t)row * 128 + (k0 ^ ((row & 7) << 3)), &ws[c * 8]);
    }
    __syncthreads();
    int lane = t & 63, w = t >> 6;
    int wr = w * 16;
    int fr = lane & 15, fk = (lane >> 4) << 3;
    f32x4 acc[8] = {};
#pragma unroll
    for (int kk = 0; kk < 4; ++kk) {
        int k0 = kk * 32 + fk;
        bf16x8 a = *(const bf16x8*)&xs[swz(wr + fr, k0)];
#pragma unroll
        for (int n = 0; n < 8; ++n) {
            bf16x8 bb = *(const bf16x8*)&ws[swz(n * 16 + fr, k0)];
            acc[n] = MFMA16(a, bb, acc[n], 0, 0, 0);
        }
    }
    __syncthreads();
#pragma unroll
    for (int n = 0; n < 8; ++n) {
        int col = n * 16 + fr;
        float bv = bias[col];
        int rl = wr + ((lane >> 4) << 2);
#pragma unroll
        for (int r = 0; r < 4; ++r) outs[(rl + r) * 132 + col] = acc[n][r] + bv;
    }
    __syncthreads();
    int row = t >> 2, oc = t & 3;
    float vals[32]; float s = 0.0f;
#pragma unroll
    for (int i = 0; i < 32; ++i) { vals[i] = outs[row * 132 + oc + 4 * i]; s += vals[i]; }
    s += __shfl_xor(s, 1, 4); s += __shfl_xor(s, 2, 4);
    float mean = s * (1.0f / 128.0f);
    float sq = 0.0f;
#pragma unroll
    for (int i = 0; i < 32; ++i) { float d = vals[i] - mean; sq += d * d; }
    sq += __shfl_xor(sq, 1, 4); sq += __shfl_xor(sq, 2, 4);
    float rs = rsqrtf(sq * (1.0f / 128.0f) + EPS);
#pragma unroll
    for (int i = 0; i < 32; ++i) {
        int c = oc + 4 * i;
        float yv = (vals[i] - mean) * rs * lns[c] + lnb[c];
        if (yf) yf[(size_t)(R + row) * 128 + c] = yv;
        Xout[(size_t)(R + row) * 128 + c] = (__bf16)yv;
    }
}

// ---------------------------------------------------------------------------
// Kernel 2 (fused, best-known config): per (bn,h): QKV GEMM (64x384, K=256)
// -> QK^T -> softmax -> PV -> bn1 LN -> At.
// X staged once; Wq slabs WAVE-PRIVATE -> K-loop has no block barriers.
// T5: s_setprio(1) around MFMA clusters (wave role-diversity exists here).
// ---------------------------------------------------------------------------
__global__ __launch_bounds__(256, 2) void qkv_attn(
    const __bf16* __restrict__ Xc, const __bf16* __restrict__ Pre,
    const __bf16* __restrict__ Wq, const float* __restrict__ bq,
    const float* __restrict__ bn1s, const float* __restrict__ bn1b,
    __bf16* __restrict__ At)
{
    __shared__ __align__(16) char lds[81920];
    unsigned short* Xs = (unsigned short*)lds;   // [64][256] 32KB
    __bf16* Qs  = (__bf16*)lds;             // [64][128] 16KB (phase 2/3 alias)
    __bf16* Ks  = (__bf16*)(lds + 16384);   // [64][128] 16KB
    __bf16* Vts = (__bf16*)(lds + 32768);   // [128][64] 16KB
    __bf16* Ps  = (__bf16*)lds;             // [64][64]  8KB, aliases Qs

    int bn = blockIdx.x >> 3, h = blockIdx.x & 7;
    int t = threadIdx.x, lane = t & 63, w = t >> 6;
    int fr = lane & 15, fk = (lane >> 4) << 3;
    int rr = (lane >> 4) << 2;
    int w16 = w * 16;
    const __bf16* Wqh = Wq + (size_t)h * 384 * 256;
    const float* bqh = bq + h * 384;
    unsigned short* slab = (unsigned short*)(lds + 32768 + w * 12288);

    // ---- stage Xs (all threads) + slab kc=0 (own wave), one barrier
#pragma unroll
    for (int i = 0; i < 8; ++i) {
        int c = t + i * 256;                // [0,2048) 16B chunks
        int row = c >> 5, k0 = (c & 31) << 3;
        int ks = k0 ^ ((row & 7) << 3);
        const __bf16* src = (ks < 128)
            ? Xc + (size_t)(bn * 64 + row) * 128 + ks
            : Pre + (size_t)(bn * 64 + row) * 128 + (ks - 128);
        gll16(src, &Xs[c * 8]);
    }
#pragma unroll
    for (int i = 0; i < 12; ++i) {
        int c = lane + i * 64;              // [0,768)
        int rl = c >> 3, k0 = (c & 7) << 3;
        gll16(Wqh + (size_t)(w * 96 + rl) * 256 + 0 * 64 + (k0 ^ ((rl & 7) << 3)),
              &slab[c * 8]);
    }
    __syncthreads();                        // B0: Xs + kc0 slabs visible

    // ---- phase 1: barrier-free K-loop.  Wave w: 64 rows x cols [w*96,+96).
    f32x4 acc[4][6] = {};
    for (int kc = 0; kc < 4; ++kc) {
        if (kc) {
            asm volatile("s_waitcnt lgkmcnt(0)" ::: "memory");
#pragma unroll
            for (int i = 0; i < 12; ++i) {
                int c = lane + i * 64;
                int rl = c >> 3, k0 = (c & 7) << 3;
                gll16(Wqh + (size_t)(w * 96 + rl) * 256 + kc * 64 + (k0 ^ ((rl & 7) << 3)),
                      &slab[c * 8]);
            }
        }
        asm volatile("s_waitcnt vmcnt(0)" ::: "memory");
        __builtin_amdgcn_sched_barrier(0);
#pragma unroll
        for (int kk = 0; kk < 2; ++kk) {
            int kl = kk * 32 + fk;              // k within 64-chunk
            int kg = kc * 64 + kl;              // k within 256
            bf16x8 a[4], b[6];
#pragma unroll
            for (int m = 0; m < 4; ++m) {
                int row = m * 16 + fr;
                a[m] = *(const bf16x8*)&Xs[row * 256 + (kg ^ ((fr & 7) << 3))];
            }
#pragma unroll
            for (int n = 0; n < 6; ++n) {
                int rl = n * 16 + fr;
                b[n] = *(const bf16x8*)&slab[rl * 64 + (kl ^ ((fr & 7) << 3))];
            }
            __builtin_amdgcn_s_setprio(1);
#pragma unroll
            for (int m = 0; m < 4; ++m)
#pragma unroll
                for (int n = 0; n < 6; ++n)
                    acc[m][n] = MFMA16(a[m], b[n], acc[m][n], 0, 0, 0);
            __builtin_amdgcn_s_setprio(0);
        }
    }
    __syncthreads();                        // B1: all slab/Xs reads done

    // ---- phase 2: +bias, scatter to Q/K/V LDS (bf16, swizzled)
#pragma unroll
    for (int n = 0; n < 6; ++n) {
        int colb = w * 96 + n * 16;
        int type = colb >> 7;                    // wave-uniform
        float bv = bqh[colb + fr];
        int f = (colb & 127) + fr;
#pragma unroll
        for (int m = 0; m < 4; ++m) {
            if (type == 2) {                     // V^T: 4 consecutive rows pack
                int rbase = m * 16 + rr;
                bf16x4 pk;
#pragma unroll
                for (int r = 0; r < 4; ++r) pk[r] = (__bf16)(acc[m][n][r] + bv);
                *(bf16x4*)&Vts[f * 64 + (rbase ^ ((f & 7) << 3))] = pk;
            } else {
#pragma unroll
                for (int r = 0; r < 4; ++r) {
                    int row = m * 16 + rr + r;
                    float val = acc[m][n][r] + bv;
                    if (type == 0)
                        Qs[row * 128 + (f ^ ((row & 7) << 3))] = (__bf16)val;
                    else
                        Ks[row * 128 + (f ^ ((row & 7) << 3))] = (__bf16)val;
                }
            }
        }
    }
    __syncthreads();                        // B2: Q/K/V ready

    // ---- phase 3a: QK^T rows [w16,+16) x 64 cols (Q rows are wave-local)
    f32x4 sacc[4] = {};
    __builtin_amdgcn_s_setprio(1);
#pragma unroll
    for (int kk = 0; kk < 4; ++kk) {
        int k0 = kk * 32 + fk;
        int arow = w16 + fr;
        bf16x8 aq = *(const bf16x8*)&Qs[arow * 128 + (k0 ^ ((arow & 7) << 3))];
#pragma unroll
        for (int n = 0; n < 4; ++n) {
            bf16x8 bk = *(const bf16x8*)&Ks[swz(n * 16 + fr, k0)];
            sacc[n] = MFMA16(aq, bk, sacc[n], 0, 0, 0);
        }
    }
    __builtin_amdgcn_s_setprio(0);
    __syncthreads();                        // B3: Qs dead -> Ps writes may alias

    // ---- phase 3b: softmax -> Ps (wave-local rows; no barrier before PV)
    const float scale = 0.08838834764831845f;   // 128^-0.5
#pragma unroll
    for (int r = 0; r < 4; ++r) {
        float sv[4];
#pragma unroll
        for (int n = 0; n < 4; ++n) sv[n] = sacc[n][r] * scale;
        float mx = fmaxf(fmaxf(sv[0], sv[1]), fmaxf(sv[2], sv[3]));
        mx = fmaxf(mx, __shfl_xor(mx, 1, 16));
        mx = fmaxf(mx, __shfl_xor(mx, 2, 16));
        mx = fmaxf(mx, __shfl_xor(mx, 4, 16));
        mx = fmaxf(mx, __shfl_xor(mx, 8, 16));
        float sum = 0.0f;
#pragma unroll
        for (int n = 0; n < 4; ++n) { sv[n] = expf(sv[n] - mx); sum += sv[n]; }
        sum += __shfl_xor(sum, 1, 16);
        sum += __shfl_xor(sum, 2, 16);
        sum += __shfl_xor(sum, 4, 16);
        sum += __shfl_xor(sum, 8, 16);
        float inv = 1.0f / sum;
        int p = w16 + rr + r;
#pragma unroll
        for (int n = 0; n < 4; ++n) {
            int q = n * 16 + fr;
            Ps[p * 64 + (q ^ ((p & 7) << 3))] = (__bf16)(sv[n] * inv);
        }
    }
    // PV reads only this wave's Ps rows -> wave-internal lgkmcnt ordering.

    // ---- phase 3c: PV rows [w16,+16) x 128 f
    f32x4 oacc[8] = {};
    __builtin_amdgcn_s_setprio(1);
#pragma unroll
    for (int kk = 0; kk < 2; ++kk) {
        int k0 = kk * 32 + fk;
        int arow = w16 + fr;
        bf16x8 ap = *(const bf16x8*)&Ps[arow * 64 + (k0 ^ ((arow & 7) << 3))];
#pragma unroll
        for (int n = 0; n < 8; ++n) {
            bf16x8 bv = *(const bf16x8*)&Vts[swz64(n * 16 + fr, k0)];
            oacc[n] = MFMA16(ap, bv, oacc[n], 0, 0, 0);
        }
    }
    __builtin_amdgcn_s_setprio(0);

    // ---- bn1 LN over f(128) + transposed bf16 write to At
#pragma unroll
    for (int r = 0; r < 4; ++r) {
        int p = w16 + rr + r;
        float s1 = 0.0f;
#pragma unroll
        for (int n = 0; n < 8; ++n) s1 += oacc[n][r];
        s1 += __shfl_xor(s1, 1, 16);
        s1 += __shfl_xor(s1, 2, 16);
        s1 += __shfl_xor(s1, 4, 16);
        s1 += __shfl_xor(s1, 8, 16);
        float mean = s1 * (1.0f / 128.0f);
        float s2 = 0.0f;
#pragma unroll
        for (int n = 0; n < 8; ++n) { float d = oacc[n][r] - mean; s2 += d * d; }
        s2 += __shfl_xor(s2, 1, 16);
        s2 += __shfl_xor(s2, 2, 16);
        s2 += __shfl_xor(s2, 4, 16);
        s2 += __shfl_xor(s2, 8, 16);
        float rs = rsqrtf(s2 * (1.0f / 128.0f) + EPS);
        __bf16* orow = At + (size_t)(bn * 64 + p) * 1024 + h * 128;
#pragma unroll
        for (int n = 0; n < 8; ++n) {
            int f = n * 16 + fr;
            orow[f] = (__bf16)((oacc[n][r] - mean) * rs * bn1s[f] + bn1b[f]);
        }
    }
}

// ---------------------------------------------------------------------------
// Kernel 3 (MFMA): proj (K=1024) + bn2 LN + gelu(cur) residual + ln_o LN
// + ffn GEMM + gelu(O_hat).  16-row tile, grid 512 -> 2 blocks/CU.
// ---------------------------------------------------------------------------
__global__ __launch_bounds__(256) void proj_ffn_mfma(
    const __bf16* __restrict__ At_g, const __bf16* __restrict__ Wp,
    const float* __restrict__ pb,
    const float* __restrict__ bn2s, const float* __restrict__ bn2b,
    const float* __restrict__ lnos, const float* __restrict__ lnob,
    const __bf16* __restrict__ Wf, const float* __restrict__ fb,
    const float* __restrict__ cur, float* __restrict__ out,
    __bf16* __restrict__ Xcur)
{
    __shared__ __align__(16) char lds[36864];
    unsigned short* ats = (unsigned short*)lds;           // [16][128] bf16 4KB
    unsigned short* wts = (unsigned short*)(lds + 4096);  // [128][128] bf16 32KB
    float* outs = (float*)lds;                            // [16][132] f32 alias
    int t = threadIdx.x;
    int R = blockIdx.x * 16;
    int lane = t & 63, w = t >> 6;
    int wcol = w * 32;
    int fr = lane & 15, fk = (lane >> 4) << 3;
    int rr = (lane >> 4) << 2;

    f32x4 acc[2] = {};
    for (int kc = 0; kc < 8; ++kc) {
        {
            int row = t >> 4, k0 = (t & 15) << 3;
            gll16(At_g + (size_t)(R + row) * 1024 + kc * 128 + (k0 ^ ((row & 7) << 3)),
                  &ats[t * 8]);
        }
#pragma unroll
        for (int i = 0; i < 8; ++i) {
            int c = t + i * 256; int row = c >> 4, k0 = (c & 15) << 3;
            gll16(Wp + (size_t)row * 1024 + kc * 128 + (k0 ^ ((row & 7) << 3)),
                  &wts[c * 8]);
        }
        __syncthreads();
#pragma unroll
        for (int kk = 0; kk < 4; ++kk) {
            int k0 = kk * 32 + fk;
            bf16x8 a = *(const bf16x8*)&ats[swz(fr, k0)];
#pragma unroll
            for (int n = 0; n < 2; ++n) {
                bf16x8 b = *(const bf16x8*)&wts[swz(wcol + n * 16 + fr, k0)];
                acc[n] = MFMA16(a, b, acc[n], 0, 0, 0);
            }
        }
        __syncthreads();
    }

#pragma unroll
    for (int n = 0; n < 2; ++n) {
        int col = wcol + n * 16 + fr;
        float bv = pb[col];
#pragma unroll
        for (int r = 0; r < 4; ++r) outs[(rr + r) * 132 + col] = acc[n][r] + bv;
    }
    __syncthreads();

    int row = t >> 4, oc = t & 15;
    float vals[8]; float s = 0.0f;
#pragma unroll
    for (int i = 0; i < 8; ++i) { vals[i] = outs[row * 132 + oc + 16 * i]; s += vals[i]; }
    s += __shfl_xor(s, 1, 16); s += __shfl_xor(s, 2, 16);
    s += __shfl_xor(s, 4, 16); s += __shfl_xor(s, 8, 16);
    float mean = s * (1.0f / 128.0f);
    float sq = 0.0f;
#pragma unroll
    for (int i = 0; i < 8; ++i) { float d = vals[i] - mean; sq += d * d; }
    sq += __shfl_xor(sq, 1, 16); sq += __shfl_xor(sq, 2, 16);
    sq += __shfl_xor(sq, 4, 16); sq += __shfl_xor(sq, 8, 16);
    float rs = rsqrtf(sq * (1.0f / 128.0f) + EPS);

    float oh[8]; float s2 = 0.0f;
#pragma unroll
    for (int i = 0; i < 8; ++i) {
        int c = oc + 16 * i;
        float ynorm = (vals[i] - mean) * rs * bn2s[c] + bn2b[c];
        float cv = cur[(size_t)(R + row) * 128 + c];
        oh[i] = cv + (ynorm + gelu_f(cv));
        s2 += oh[i];
    }
    s2 += __shfl_xor(s2, 1, 16); s2 += __shfl_xor(s2, 2, 16);
    s2 += __shfl_xor(s2, 4, 16); s2 += __shfl_xor(s2, 8, 16);
    float mean2 = s2 * (1.0f / 128.0f);
    float sq2 = 0.0f;
#pragma unroll
    for (int i = 0; i < 8; ++i) { float d = oh[i] - mean2; sq2 += d * d; }
    sq2 += __shfl_xor(sq2, 1, 16); sq2 += __shfl_xor(sq2, 2, 16);
    sq2 += __shfl_xor(sq2, 4, 16); sq2 += __shfl_xor(sq2, 8, 16);
    float rs2 = rsqrtf(sq2 * (1.0f / 128.0f) + EPS);
#pragma unroll
    for (int i = 0; i < 8; ++i) {
        int c = oc + 16 * i;
        oh[i] = (oh[i] - mean2) * rs2 * lnos[c] + lnob[c];   // O_hat
    }
    __syncthreads();

#pragma unroll
    for (int i = 0; i < 8; ++i) {
        int c = oc + 16 * i;
        ((__bf16*)ats)[row * 128 + (c ^ ((row & 7) << 3))] = (__bf16)oh[i];
    }
#pragma unroll
    for (int i = 0; i < 8; ++i) {
        int c = t + i * 256; int rw = c >> 4, k0 = (c & 15) << 3;
        gll16(Wf + (size_t)rw * 128 + (k0 ^ ((rw & 7) << 3)), &wts[c * 8]);
    }
    __syncthreads();

    f32x4 acc2[2] = {};
#pragma unroll
    for (int kk = 0; kk < 4; ++kk) {
        int k0 = kk * 32 + fk;
        bf16x8 a = *(const bf16x8*)&ats[swz(fr, k0)];
#pragma unroll
        for (int n = 0; n < 2; ++n) {
            bf16x8 b = *(const bf16x8*)&wts[swz(wcol + n * 16 + fr, k0)];
            acc2[n] = MFMA16(a, b, acc2[n], 0, 0, 0);
        }
    }
#pragma unroll
    for (int n = 0; n < 2; ++n) {
        int col = wcol + n * 16 + fr;
        float bv = fb[col];
#pragma unroll
        for (int r = 0; r < 4; ++r) {
            int ro = rr + r;
            float ov = (float)((__bf16*)ats)[ro * 128 + (col ^ ((ro & 7) << 3))];
            float val = acc2[n][r] + bv + gelu_f(ov);
            size_t gidx = (size_t)(R + ro) * 128 + col;
            out[gidx] = val;
            if (Xcur) Xcur[gidx] = (__bf16)val;
        }
    }
}

// ---------------------------------------------------------------------------
extern "C" void kernel_launch(void* const* d_in, const int* in_sizes, int n_in,
                              void* d_out, int out_size, void* d_ws, size_t ws_size,
                              hipStream_t stream)
{
    const float* seq       = (const float*)d_in[0];
    const float* Hpre      = (const float*)d_in[1];
    const float* pro1_w    = (const float*)d_in[2];
    const float* pro1_b    = (const float*)d_in[3];
    const float* pro2_w    = (const float*)d_in[4];
    const float* pro2_b    = (const float*)d_in[5];
    const float* ln_cur_s  = (const float*)d_in[6];
    const float* ln_cur_b  = (const float*)d_in[7];
    const float* ln_pre_s  = (const float*)d_in[8];
    const float* ln_pre_b  = (const float*)d_in[9];
    const float* cur_qkv_w = (const float*)d_in[10];
    const float* cur_qkv_b = (const float*)d_in[11];
    const float* pre_qkv_w = (const float*)d_in[12];
    const float* pre_qkv_b = (const float*)d_in[13];
    const float* alpha     = (const float*)d_in[14];
    const float* proj_w    = (const float*)d_in[15];
    const float* proj_b    = (const float*)d_in[16];
    const float* bn1_s     = (const float*)d_in[17];
    const float* bn1_b     = (const float*)d_in[18];
    const float* bn2_s     = (const float*)d_in[19];
    const float* bn2_b     = (const float*)d_in[20];
    const float* ln_o_s    = (const float*)d_in[21];
    const float* ln_o_b    = (const float*)d_in[22];
    const float* ffn_w     = (const float*)d_in[23];
    const float* ffn_b     = (const float*)d_in[24];

    char* ws = (char*)d_ws;
    __bf16* Wq      = (__bf16*)ws;                 ws += (size_t)4 * 3072 * 256 * 2;
    float*  bq      = (float*)ws;                  ws += (size_t)4 * 3072 * 4;
    __bf16* Wp_bf   = (__bf16*)ws;                 ws += (size_t)4 * 128 * 1024 * 2;
    __bf16* Wf_bf   = (__bf16*)ws;                 ws += (size_t)4 * 128 * 128 * 2;
    __bf16* pro1_bf = (__bf16*)ws;                 ws += (size_t)128 * 128 * 2;
    __bf16* pro2_bf = (__bf16*)ws;                 ws += (size_t)4 * 128 * 128 * 2;
    __bf16* Xc   = (__bf16*)ws;                    ws += (size_t)8192 * 128 * 2;
    __bf16* preb = (__bf16*)ws;                    ws += (size_t)4 * 8192 * 128 * 2;
    float*  cur  = (float*)ws;                     ws += (size_t)8192 * 128 * 4;
    __bf16* Atb  = (__bf16*)ws;                    ws += (size_t)8192 * 1024 * 2;

    prep_all<<<2192, 256, 0, stream>>>(
        cur_qkv_w, cur_qkv_b, pre_qkv_w, pre_qkv_b, alpha, Wq, bq,
        proj_w, Wp_bf, 4 * 128 * 1024,
        ffn_w, Wf_bf, 4 * 128 * 128,
        pro1_w, pro1_bf, 128 * 128,
        pro2_w, pro2_bf, 4 * 128 * 128);
    lin_all<<<640, 256, 0, stream>>>(Hpre, pro2_bf, pro2_b, ln_pre_s, ln_pre_b,
                                     preb, seq, pro1_bf, pro1_b,
                                     ln_cur_s, ln_cur_b, cur, Xc);

    for (int l = 0; l < 4; ++l) {
        qkv_attn<<<1024, 256, 0, stream>>>(
            Xc, preb + (size_t)l * 8192 * 128,
            Wq + (size_t)l * 3072 * 256, bq + l * 3072,
            bn1_s + l * 128, bn1_b + l * 128, Atb);
        float* outp = (l == 3) ? (float*)d_out : cur;
        proj_ffn_mfma<<<512, 256, 0, stream>>>(Atb,
                                               Wp_bf + (size_t)l * 128 * 1024,
                                               proj_b + l * 128,
                                               bn2_s + l * 128, bn2_b + l * 128,
                                               ln_o_s + l * 128, ln_o_b + l * 128,
                                               Wf_bf + (size_t)l * 16384,
                                               ffn_b + l * 128,
                                               cur, outp, (l == 3) ? nullptr : Xc);
    }
}

// Round 17
// 218.216 us; speedup vs baseline: 1.0472x; 1.0139x over previous
//
#include <hip/hip_runtime.h>
#include <math.h>

#define EPS 1e-5f

// L=4, B=16, N=8, P=64, D=128, F=128, H=8
// M = B*N*P = 8192 rows, HF = 1024, QKV width = 3072

typedef __bf16 bf16x8 __attribute__((ext_vector_type(8)));
typedef __bf16 bf16x4 __attribute__((ext_vector_type(4)));
typedef float f32x4 __attribute__((ext_vector_type(4)));

#define MFMA16 __builtin_amdgcn_mfma_f32_16x16x32_bf16

__device__ __forceinline__ float gelu_f(float x) {
    return 0.5f * x * (1.0f + erff(x * 0.7071067811865476f));
}

// async 16B global->LDS (linear dest, per-lane source)
__device__ __forceinline__ void gll16(const void* g, void* l) {
    __builtin_amdgcn_global_load_lds(
        (const __attribute__((address_space(1))) void*)g,
        (__attribute__((address_space(3))) void*)l, 16, 0, 0);
}

__device__ __forceinline__ void cvt_store8(void* dst, const float* __restrict__ src) {
    float4 a = ((const float4*)src)[0];
    float4 b = ((const float4*)src)[1];
    bf16x8 v;
    v[0] = (__bf16)a.x; v[1] = (__bf16)a.y; v[2] = (__bf16)a.z; v[3] = (__bf16)a.w;
    v[4] = (__bf16)b.x; v[5] = (__bf16)b.y; v[6] = (__bf16)b.z; v[7] = (__bf16)b.w;
    *(bf16x8*)dst = v;
}

// XOR swizzles (period-8 row stripe, 16B granules)
__device__ __forceinline__ int swz(int row, int k0)   { return row * 128 + (k0 ^ ((row & 7) << 3)); }
__device__ __forceinline__ int swz64(int row, int k0) { return row * 64  + (k0 ^ ((row & 7) << 3)); }

// ---------------------------------------------------------------------------
// Prep (merged): blocks [0,1536): blend-folded QKV weight (per-head layout
// Wq[l][h*384+type*128+f][256]) + bias.  Blocks [1536,2192): f32->bf16 cvt.
// ---------------------------------------------------------------------------
__global__ __launch_bounds__(256) void prep_all(
    const float* __restrict__ Wc, const float* __restrict__ bc,
    const float* __restrict__ Wpq, const float* __restrict__ bp,
    const float* __restrict__ alpha,
    __bf16* __restrict__ Wq, float* __restrict__ bq,
    const float* __restrict__ s0, __bf16* __restrict__ d0, int n0,
    const float* __restrict__ s1, __bf16* __restrict__ d1, int n1,
    const float* __restrict__ s2, __bf16* __restrict__ d2, int n2,
    const float* __restrict__ s3, __bf16* __restrict__ d3, int n3)
{
    int b = blockIdx.x;
    if (b < 1536) {
        int idx = b * 256 + threadIdx.x;               // [0, 393216)
        int l = idx / 98304, rem = idx - l * 98304;    // 98304 = 3072*32
        int row = rem >> 5, g = rem & 31, k0 = g << 3; // row: type*1024+h*128+f
        int type = row >> 10, hf = row & 1023, h = hf >> 7, f = hf & 127;
        int rowp = h * 384 + type * 128 + f;
        float a = 1.0f / (1.0f + expf(-alpha[l * 3072 + row]));
        __bf16* dst = Wq + ((size_t)l * 3072 + rowp) * 256 + k0;
        if (k0 < 128) {
            const float* s = Wc + ((size_t)l * 3072 + row) * 128 + k0;
#pragma unroll
            for (int j = 0; j < 8; ++j) dst[j] = (__bf16)(a * s[j]);
        } else {
            const float* s = Wpq + ((size_t)l * 3072 + row) * 128 + (k0 - 128);
#pragma unroll
            for (int j = 0; j < 8; ++j) dst[j] = (__bf16)((1.0f - a) * s[j]);
        }
        if (g == 0)
            bq[l * 3072 + rowp] = a * bc[l * 3072 + row] + (1.0f - a) * bp[l * 3072 + row];
    } else {
        int off = ((b - 1536) * 256 + threadIdx.x) * 4;
        const float* s; __bf16* d;
        if (off < n0) { s = s0; d = d0; }
        else {
            off -= n0;
            if (off < n1) { s = s1; d = d1; }
            else {
                off -= n1;
                if (off < n2) { s = s2; d = d2; }
                else {
                    off -= n2;
                    if (off >= n3) return;
                    s = s3; d = d3;
                }
            }
        }
        float4 v = *(const float4*)(s + off);
        d[off] = (__bf16)v.x; d[off + 1] = (__bf16)v.y;
        d[off + 2] = (__bf16)v.z; d[off + 3] = (__bf16)v.w;
    }
}

// ---------------------------------------------------------------------------
// Kernel 1 (merged lin): 64-row tiles.
// blocks [0,512): pre[l] = LN(Hpre[l] @ pro2[l]^T + b)   (l = b>>7)
// blocks [512,640): cur  = LN(seq @ pro1^T + b) -> f32 cur + bf16 Xc
// ---------------------------------------------------------------------------
__global__ __launch_bounds__(256) void lin_all(
    const float* __restrict__ Hpre, const __bf16* __restrict__ pro2b,
    const float* __restrict__ pro2bias,
    const float* __restrict__ lnps, const float* __restrict__ lnpb,
    __bf16* __restrict__ preb,
    const float* __restrict__ seq, const __bf16* __restrict__ pro1b,
    const float* __restrict__ pro1bias,
    const float* __restrict__ lncs, const float* __restrict__ lncb,
    float* __restrict__ curf, __bf16* __restrict__ Xcb)
{
    __shared__ __align__(16) char lds[49152];
    unsigned short* xs = (unsigned short*)lds;            // [64][128] 16KB
    unsigned short* ws = (unsigned short*)(lds + 16384);  // [128][128] 32KB
    float* outs = (float*)lds;                            // [64][132] alias
    int b = blockIdx.x, t = threadIdx.x;
    const float* x; const __bf16* W; const float* bias;
    const float* lns; const float* lnb;
    float* yf = nullptr; __bf16* Xout; int R;
    if (b < 512) {
        int l = b >> 7; R = (b & 127) * 64;
        x = Hpre + (size_t)l * 8192 * 128;
        W = pro2b + (size_t)l * 16384;
        bias = pro2bias + l * 128; lns = lnps + l * 128; lnb = lnpb + l * 128;
        Xout = preb + (size_t)l * 8192 * 128;
    } else {
        R = (b - 512) * 64;
        x = seq; W = pro1b; bias = pro1bias; lns = lncs; lnb = lncb;
        yf = curf; Xout = Xcb;
    }
#pragma unroll
    for (int i = 0; i < 4; ++i) {
        int c = t + i * 256; int row = c >> 4, k0 = (c & 15) << 3;
        cvt_store8(&xs[swz(row, k0)], x + (size_t)(R + row) * 128 + k0);
    }
#pragma unroll
    for (int i = 0; i < 8; ++i) {
        int c = t + i * 256; int row = c >> 4, k0 = (c & 15) << 3;
        gll16(W + (size_t)row * 128 + (k0 ^ ((row & 7) << 3)), &ws[c * 8]);
    }
    __syncthreads();
    int lane = t & 63, w = t >> 6;
    int wr = w * 16;
    int fr = lane & 15, fk = (lane >> 4) << 3;
    f32x4 acc[8] = {};
#pragma unroll
    for (int kk = 0; kk < 4; ++kk) {
        int k0 = kk * 32 + fk;
        bf16x8 a = *(const bf16x8*)&xs[swz(wr + fr, k0)];
#pragma unroll
        for (int n = 0; n < 8; ++n) {
            bf16x8 bb = *(const bf16x8*)&ws[swz(n * 16 + fr, k0)];
            acc[n] = MFMA16(a, bb, acc[n], 0, 0, 0);
        }
    }
    __syncthreads();
#pragma unroll
    for (int n = 0; n < 8; ++n) {
        int col = n * 16 + fr;
        float bv = bias[col];
        int rl = wr + ((lane >> 4) << 2);
#pragma unroll
        for (int r = 0; r < 4; ++r) outs[(rl + r) * 132 + col] = acc[n][r] + bv;
    }
    __syncthreads();
    int row = t >> 2, oc = t & 3;
    float vals[32]; float s = 0.0f;
#pragma unroll
    for (int i = 0; i < 32; ++i) { vals[i] = outs[row * 132 + oc + 4 * i]; s += vals[i]; }
    s += __shfl_xor(s, 1, 4); s += __shfl_xor(s, 2, 4);
    float mean = s * (1.0f / 128.0f);
    float sq = 0.0f;
#pragma unroll
    for (int i = 0; i < 32; ++i) { float d = vals[i] - mean; sq += d * d; }
    sq += __shfl_xor(sq, 1, 4); sq += __shfl_xor(sq, 2, 4);
    float rs = rsqrtf(sq * (1.0f / 128.0f) + EPS);
#pragma unroll
    for (int i = 0; i < 32; ++i) {
        int c = oc + 4 * i;
        float yv = (vals[i] - mean) * rs * lns[c] + lnb[c];
        if (yf) yf[(size_t)(R + row) * 128 + c] = yv;
        Xout[(size_t)(R + row) * 128 + c] = (__bf16)yv;
    }
}

// ---------------------------------------------------------------------------
// Kernel 2 (fused, best-known config): per (bn,h): QKV GEMM (64x384, K=256)
// -> QK^T -> softmax -> PV -> bn1 LN -> At.
// X staged once; Wq slabs WAVE-PRIVATE -> K-loop has no block barriers.
// ---------------------------------------------------------------------------
__global__ __launch_bounds__(256, 2) void qkv_attn(
    const __bf16* __restrict__ Xc, const __bf16* __restrict__ Pre,
    const __bf16* __restrict__ Wq, const float* __restrict__ bq,
    const float* __restrict__ bn1s, const float* __restrict__ bn1b,
    __bf16* __restrict__ At)
{
    __shared__ __align__(16) char lds[81920];
    unsigned short* Xs = (unsigned short*)lds;   // [64][256] 32KB
    __bf16* Qs  = (__bf16*)lds;             // [64][128] 16KB (phase 2/3 alias)
    __bf16* Ks  = (__bf16*)(lds + 16384);   // [64][128] 16KB
    __bf16* Vts = (__bf16*)(lds + 32768);   // [128][64] 16KB
    __bf16* Ps  = (__bf16*)lds;             // [64][64]  8KB, aliases Qs

    int bn = blockIdx.x >> 3, h = blockIdx.x & 7;
    int t = threadIdx.x, lane = t & 63, w = t >> 6;
    int fr = lane & 15, fk = (lane >> 4) << 3;
    int rr = (lane >> 4) << 2;
    int w16 = w * 16;
    const __bf16* Wqh = Wq + (size_t)h * 384 * 256;
    const float* bqh = bq + h * 384;
    unsigned short* slab = (unsigned short*)(lds + 32768 + w * 12288);

    // ---- stage Xs (all threads) + slab kc=0 (own wave), one barrier
#pragma unroll
    for (int i = 0; i < 8; ++i) {
        int c = t + i * 256;                // [0,2048) 16B chunks
        int row = c >> 5, k0 = (c & 31) << 3;
        int ks = k0 ^ ((row & 7) << 3);
        const __bf16* src = (ks < 128)
            ? Xc + (size_t)(bn * 64 + row) * 128 + ks
            : Pre + (size_t)(bn * 64 + row) * 128 + (ks - 128);
        gll16(src, &Xs[c * 8]);
    }
#pragma unroll
    for (int i = 0; i < 12; ++i) {
        int c = lane + i * 64;              // [0,768)
        int rl = c >> 3, k0 = (c & 7) << 3;
        gll16(Wqh + (size_t)(w * 96 + rl) * 256 + 0 * 64 + (k0 ^ ((rl & 7) << 3)),
              &slab[c * 8]);
    }
    __syncthreads();                        // B0: Xs + kc0 slabs visible

    // ---- phase 1: barrier-free K-loop.  Wave w: 64 rows x cols [w*96,+96).
    f32x4 acc[4][6] = {};
    for (int kc = 0; kc < 4; ++kc) {
        if (kc) {
            asm volatile("s_waitcnt lgkmcnt(0)" ::: "memory");
#pragma unroll
            for (int i = 0; i < 12; ++i) {
                int c = lane + i * 64;
                int rl = c >> 3, k0 = (c & 7) << 3;
                gll16(Wqh + (size_t)(w * 96 + rl) * 256 + kc * 64 + (k0 ^ ((rl & 7) << 3)),
                      &slab[c * 8]);
            }
        }
        asm volatile("s_waitcnt vmcnt(0)" ::: "memory");
        __builtin_amdgcn_sched_barrier(0);
#pragma unroll
        for (int kk = 0; kk < 2; ++kk) {
            int kl = kk * 32 + fk;              // k within 64-chunk
            int kg = kc * 64 + kl;              // k within 256
            bf16x8 a[4], b[6];
#pragma unroll
            for (int m = 0; m < 4; ++m) {
                int row = m * 16 + fr;
                a[m] = *(const bf16x8*)&Xs[row * 256 + (kg ^ ((fr & 7) << 3))];
            }
#pragma unroll
            for (int n = 0; n < 6; ++n) {
                int rl = n * 16 + fr;
                b[n] = *(const bf16x8*)&slab[rl * 64 + (kl ^ ((fr & 7) << 3))];
            }
            __builtin_amdgcn_s_setprio(1);
#pragma unroll
            for (int m = 0; m < 4; ++m)
#pragma unroll
                for (int n = 0; n < 6; ++n)
                    acc[m][n] = MFMA16(a[m], b[n], acc[m][n], 0, 0, 0);
            __builtin_amdgcn_s_setprio(0);
        }
    }
    __syncthreads();                        // B1: all slab/Xs reads done

    // ---- phase 2: +bias, scatter to Q/K/V LDS (bf16, swizzled)
#pragma unroll
    for (int n = 0; n < 6; ++n) {
        int colb = w * 96 + n * 16;
        int type = colb >> 7;                    // wave-uniform
        float bv = bqh[colb + fr];
        int f = (colb & 127) + fr;
#pragma unroll
        for (int m = 0; m < 4; ++m) {
            if (type == 2) {                     // V^T: 4 consecutive rows pack
                int rbase = m * 16 + rr;
                bf16x4 pk;
#pragma unroll
                for (int r = 0; r < 4; ++r) pk[r] = (__bf16)(acc[m][n][r] + bv);
                *(bf16x4*)&Vts[f * 64 + (rbase ^ ((f & 7) << 3))] = pk;
            } else {
#pragma unroll
                for (int r = 0; r < 4; ++r) {
                    int row = m * 16 + rr + r;
                    float val = acc[m][n][r] + bv;
                    if (type == 0)
                        Qs[row * 128 + (f ^ ((row & 7) << 3))] = (__bf16)val;
                    else
                        Ks[row * 128 + (f ^ ((row & 7) << 3))] = (__bf16)val;
                }
            }
        }
    }
    __syncthreads();                        // B2: Q/K/V ready

    // ---- phase 3a: QK^T rows [w16,+16) x 64 cols (Q rows are wave-local)
    f32x4 sacc[4] = {};
    __builtin_amdgcn_s_setprio(1);
#pragma unroll
    for (int kk = 0; kk < 4; ++kk) {
        int k0 = kk * 32 + fk;
        int arow = w16 + fr;
        bf16x8 aq = *(const bf16x8*)&Qs[arow * 128 + (k0 ^ ((arow & 7) << 3))];
#pragma unroll
        for (int n = 0; n < 4; ++n) {
            bf16x8 bk = *(const bf16x8*)&Ks[swz(n * 16 + fr, k0)];
            sacc[n] = MFMA16(aq, bk, sacc[n], 0, 0, 0);
        }
    }
    __builtin_amdgcn_s_setprio(0);
    __syncthreads();                        // B3: Qs dead -> Ps writes may alias

    // ---- phase 3b: softmax -> Ps (wave-local rows; no barrier before PV)
    const float scale = 0.08838834764831845f;   // 128^-0.5
#pragma unroll
    for (int r = 0; r < 4; ++r) {
        float sv[4];
#pragma unroll
        for (int n = 0; n < 4; ++n) sv[n] = sacc[n][r] * scale;
        float mx = fmaxf(fmaxf(sv[0], sv[1]), fmaxf(sv[2], sv[3]));
        mx = fmaxf(mx, __shfl_xor(mx, 1, 16));
        mx = fmaxf(mx, __shfl_xor(mx, 2, 16));
        mx = fmaxf(mx, __shfl_xor(mx, 4, 16));
        mx = fmaxf(mx, __shfl_xor(mx, 8, 16));
        float sum = 0.0f;
#pragma unroll
        for (int n = 0; n < 4; ++n) { sv[n] = expf(sv[n] - mx); sum += sv[n]; }
        sum += __shfl_xor(sum, 1, 16);
        sum += __shfl_xor(sum, 2, 16);
        sum += __shfl_xor(sum, 4, 16);
        sum += __shfl_xor(sum, 8, 16);
        float inv = 1.0f / sum;
        int p = w16 + rr + r;
#pragma unroll
        for (int n = 0; n < 4; ++n) {
            int q = n * 16 + fr;
            Ps[p * 64 + (q ^ ((p & 7) << 3))] = (__bf16)(sv[n] * inv);
        }
    }
    // PV reads only this wave's Ps rows -> wave-internal lgkmcnt ordering.

    // ---- phase 3c: PV rows [w16,+16) x 128 f
    f32x4 oacc[8] = {};
    __builtin_amdgcn_s_setprio(1);
#pragma unroll
    for (int kk = 0; kk < 2; ++kk) {
        int k0 = kk * 32 + fk;
        int arow = w16 + fr;
        bf16x8 ap = *(const bf16x8*)&Ps[arow * 64 + (k0 ^ ((arow & 7) << 3))];
#pragma unroll
        for (int n = 0; n < 8; ++n) {
            bf16x8 bv = *(const bf16x8*)&Vts[swz64(n * 16 + fr, k0)];
            oacc[n] = MFMA16(ap, bv, oacc[n], 0, 0, 0);
        }
    }
    __builtin_amdgcn_s_setprio(0);

    // ---- bn1 LN over f(128) + transposed bf16 write to At
#pragma unroll
    for (int r = 0; r < 4; ++r) {
        int p = w16 + rr + r;
        float s1 = 0.0f;
#pragma unroll
        for (int n = 0; n < 8; ++n) s1 += oacc[n][r];
        s1 += __shfl_xor(s1, 1, 16);
        s1 += __shfl_xor(s1, 2, 16);
        s1 += __shfl_xor(s1, 4, 16);
        s1 += __shfl_xor(s1, 8, 16);
        float mean = s1 * (1.0f / 128.0f);
        float s2 = 0.0f;
#pragma unroll
        for (int n = 0; n < 8; ++n) { float d = oacc[n][r] - mean; s2 += d * d; }
        s2 += __shfl_xor(s2, 1, 16);
        s2 += __shfl_xor(s2, 2, 16);
        s2 += __shfl_xor(s2, 4, 16);
        s2 += __shfl_xor(s2, 8, 16);
        float rs = rsqrtf(s2 * (1.0f / 128.0f) + EPS);
        __bf16* orow = At + (size_t)(bn * 64 + p) * 1024 + h * 128;
#pragma unroll
        for (int n = 0; n < 8; ++n) {
            int f = n * 16 + fr;
            orow[f] = (__bf16)((oacc[n][r] - mean) * rs * bn1s[f] + bn1b[f]);
        }
    }
}

// ---------------------------------------------------------------------------
// Kernel 3 (MFMA, wave-private slabs): proj (K=1024) + bn2 LN + gelu(cur)
// residual + ln_o LN + ffn GEMM + gelu(O_hat).  16-row tile, grid 512.
// At staged once (16x1024, 32KB); Wp slabs WAVE-PRIVATE ([32][128], 8KB each)
// -> K-loop has no block barriers (per-wave lgkm/vmcnt waits only).
// ---------------------------------------------------------------------------
__global__ __launch_bounds__(256, 2) void proj_ffn_mfma(
    const __bf16* __restrict__ At_g, const __bf16* __restrict__ Wp,
    const float* __restrict__ pb,
    const float* __restrict__ bn2s, const float* __restrict__ bn2b,
    const float* __restrict__ lnos, const float* __restrict__ lnob,
    const __bf16* __restrict__ Wf, const float* __restrict__ fb,
    const float* __restrict__ cur, float* __restrict__ out,
    __bf16* __restrict__ Xcur)
{
    __shared__ __align__(16) char lds[65536];
    unsigned short* ats = (unsigned short*)lds;           // [16][1024] 32KB (ph1)
    float* outs = (float*)lds;                            // [16][132] f32 alias
    __bf16* ohs = (__bf16*)(lds + 16384);                 // [16][128] 4KB (ph3)
    unsigned short* wfs = (unsigned short*)(lds + 32768); // [128][128] 32KB (ph3)
    int t = threadIdx.x;
    int R = blockIdx.x * 16;
    int lane = t & 63, w = t >> 6;
    int wcol = w * 32;
    int fr = lane & 15, fk = (lane >> 4) << 3;
    int rr = (lane >> 4) << 2;
    unsigned short* slab = (unsigned short*)(lds + 32768 + w * 8192); // [32][128]

    // ---- stage full At tile (all threads) + slab kc=0 (own wave)
#pragma unroll
    for (int i = 0; i < 8; ++i) {
        int c = t + i * 256;                // [0,2048): row = c>>7, k0 = (c&127)<<3
        int row = c >> 7, k0 = (c & 127) << 3;
        gll16(At_g + (size_t)(R + row) * 1024 + (k0 ^ ((row & 7) << 3)), &ats[c * 8]);
    }
#pragma unroll
    for (int i = 0; i < 8; ++i) {
        int c = lane + i * 64;              // [0,512): rl = c>>4, k0 = (c&15)<<3
        int rl = c >> 4, k0 = (c & 15) << 3;
        gll16(Wp + (size_t)(wcol + rl) * 1024 + 0 * 128 + (k0 ^ ((rl & 7) << 3)),
              &slab[c * 8]);
    }
    __syncthreads();                        // B0: At + kc0 slabs visible

    // ---- phase 1: barrier-free K-loop (8 chunks of K=128)
    f32x4 acc[2] = {};
    for (int kc = 0; kc < 8; ++kc) {
        if (kc) {
            asm volatile("s_waitcnt lgkmcnt(0)" ::: "memory");
#pragma unroll
            for (int i = 0; i < 8; ++i) {
                int c = lane + i * 64;
                int rl = c >> 4, k0 = (c & 15) << 3;
                gll16(Wp + (size_t)(wcol + rl) * 1024 + kc * 128 + (k0 ^ ((rl & 7) << 3)),
                      &slab[c * 8]);
            }
        }
        asm volatile("s_waitcnt vmcnt(0)" ::: "memory");
        __builtin_amdgcn_sched_barrier(0);
#pragma unroll
        for (int kk = 0; kk < 4; ++kk) {
            int kl = kk * 32 + fk;              // k within 128-chunk
            int kg = kc * 128 + kl;             // k within 1024
            bf16x8 a = *(const bf16x8*)&ats[fr * 1024 + (kg ^ ((fr & 7) << 3))];
            bf16x8 b0 = *(const bf16x8*)&slab[(fr) * 128 + (kl ^ ((fr & 7) << 3))];
            bf16x8 b1 = *(const bf16x8*)&slab[(16 + fr) * 128 + (kl ^ (((16 + fr) & 7) << 3))];
            __builtin_amdgcn_s_setprio(1);
            acc[0] = MFMA16(a, b0, acc[0], 0, 0, 0);
            acc[1] = MFMA16(a, b1, acc[1], 0, 0, 0);
            __builtin_amdgcn_s_setprio(0);
        }
    }
    __syncthreads();                        // B1: all ats/slab reads done

    // ---- dump acc(+bias) to outs (aliases ats)
#pragma unroll
    for (int n = 0; n < 2; ++n) {
        int col = wcol + n * 16 + fr;
        float bv = pb[col];
#pragma unroll
        for (int r = 0; r < 4; ++r) outs[(rr + r) * 132 + col] = acc[n][r] + bv;
    }
    __syncthreads();                        // B2: outs ready

    // ---- phase 2: bn2 LN -> +gelu(cur) residual -> ln_o LN (16 lanes/row)
    int row = t >> 4, oc = t & 15;
    float vals[8]; float s = 0.0f;
#pragma unroll
    for (int i = 0; i < 8; ++i) { vals[i] = outs[row * 132 + oc + 16 * i]; s += vals[i]; }
    s += __shfl_xor(s, 1, 16); s += __shfl_xor(s, 2, 16);
    s += __shfl_xor(s, 4, 16); s += __shfl_xor(s, 8, 16);
    float mean = s * (1.0f / 128.0f);
    float sq = 0.0f;
#pragma unroll
    for (int i = 0; i < 8; ++i) { float d = vals[i] - mean; sq += d * d; }
    sq += __shfl_xor(sq, 1, 16); sq += __shfl_xor(sq, 2, 16);
    sq += __shfl_xor(sq, 4, 16); sq += __shfl_xor(sq, 8, 16);
    float rs = rsqrtf(sq * (1.0f / 128.0f) + EPS);

    float oh[8]; float s2 = 0.0f;
#pragma unroll
    for (int i = 0; i < 8; ++i) {
        int c = oc + 16 * i;
        float ynorm = (vals[i] - mean) * rs * bn2s[c] + bn2b[c];
        float cv = cur[(size_t)(R + row) * 128 + c];
        oh[i] = cv + (ynorm + gelu_f(cv));
        s2 += oh[i];
    }
    s2 += __shfl_xor(s2, 1, 16); s2 += __shfl_xor(s2, 2, 16);
    s2 += __shfl_xor(s2, 4, 16); s2 += __shfl_xor(s2, 8, 16);
    float mean2 = s2 * (1.0f / 128.0f);
    float sq2 = 0.0f;
#pragma unroll
    for (int i = 0; i < 8; ++i) { float d = oh[i] - mean2; sq2 += d * d; }
    sq2 += __shfl_xor(sq2, 1, 16); sq2 += __shfl_xor(sq2, 2, 16);
    sq2 += __shfl_xor(sq2, 4, 16); sq2 += __shfl_xor(sq2, 8, 16);
    float rs2 = rsqrtf(sq2 * (1.0f / 128.0f) + EPS);
#pragma unroll
    for (int i = 0; i < 8; ++i) {
        int c = oc + 16 * i;
        oh[i] = (oh[i] - mean2) * rs2 * lnos[c] + lnob[c];   // O_hat
    }

    // ---- phase 3: stage O_hat (bf16, swizzled) + Wf, ffn GEMM + gelu
#pragma unroll
    for (int i = 0; i < 8; ++i) {
        int c = oc + 16 * i;
        ohs[row * 128 + (c ^ ((row & 7) << 3))] = (__bf16)oh[i];
    }
#pragma unroll
    for (int i = 0; i < 8; ++i) {
        int c = t + i * 256; int rw = c >> 4, k0 = (c & 15) << 3;
        gll16(Wf + (size_t)rw * 128 + (k0 ^ ((rw & 7) << 3)), &wfs[c * 8]);
    }
    __syncthreads();                        // B3: O_hat + Wf ready

    f32x4 acc2[2] = {};
#pragma unroll
    for (int kk = 0; kk < 4; ++kk) {
        int k0 = kk * 32 + fk;
        bf16x8 a = *(const bf16x8*)&ohs[fr * 128 + (k0 ^ ((fr & 7) << 3))];
#pragma unroll
        for (int n = 0; n < 2; ++n) {
            bf16x8 b = *(const bf16x8*)&wfs[swz(wcol + n * 16 + fr, k0)];
            acc2[n] = MFMA16(a, b, acc2[n], 0, 0, 0);
        }
    }
#pragma unroll
    for (int n = 0; n < 2; ++n) {
        int col = wcol + n * 16 + fr;
        float bv = fb[col];
#pragma unroll
        for (int r = 0; r < 4; ++r) {
            int ro = rr + r;
            float ov = (float)ohs[ro * 128 + (col ^ ((ro & 7) << 3))];
            float val = acc2[n][r] + bv + gelu_f(ov);
            size_t gidx = (size_t)(R + ro) * 128 + col;
            out[gidx] = val;
            if (Xcur) Xcur[gidx] = (__bf16)val;
        }
    }
}

// ---------------------------------------------------------------------------
extern "C" void kernel_launch(void* const* d_in, const int* in_sizes, int n_in,
                              void* d_out, int out_size, void* d_ws, size_t ws_size,
                              hipStream_t stream)
{
    const float* seq       = (const float*)d_in[0];
    const float* Hpre      = (const float*)d_in[1];
    const float* pro1_w    = (const float*)d_in[2];
    const float* pro1_b    = (const float*)d_in[3];
    const float* pro2_w    = (const float*)d_in[4];
    const float* pro2_b    = (const float*)d_in[5];
    const float* ln_cur_s  = (const float*)d_in[6];
    const float* ln_cur_b  = (const float*)d_in[7];
    const float* ln_pre_s  = (const float*)d_in[8];
    const float* ln_pre_b  = (const float*)d_in[9];
    const float* cur_qkv_w = (const float*)d_in[10];
    const float* cur_qkv_b = (const float*)d_in[11];
    const float* pre_qkv_w = (const float*)d_in[12];
    const float* pre_qkv_b = (const float*)d_in[13];
    const float* alpha     = (const float*)d_in[14];
    const float* proj_w    = (const float*)d_in[15];
    const float* proj_b    = (const float*)d_in[16];
    const float* bn1_s     = (const float*)d_in[17];
    const float* bn1_b     = (const float*)d_in[18];
    const float* bn2_s     = (const float*)d_in[19];
    const float* bn2_b     = (const float*)d_in[20];
    const float* ln_o_s    = (const float*)d_in[21];
    const float* ln_o_b    = (const float*)d_in[22];
    const float* ffn_w     = (const float*)d_in[23];
    const float* ffn_b     = (const float*)d_in[24];

    char* ws = (char*)d_ws;
    __bf16* Wq      = (__bf16*)ws;                 ws += (size_t)4 * 3072 * 256 * 2;
    float*  bq      = (float*)ws;                  ws += (size_t)4 * 3072 * 4;
    __bf16* Wp_bf   = (__bf16*)ws;                 ws += (size_t)4 * 128 * 1024 * 2;
    __bf16* Wf_bf   = (__bf16*)ws;                 ws += (size_t)4 * 128 * 128 * 2;
    __bf16* pro1_bf = (__bf16*)ws;                 ws += (size_t)128 * 128 * 2;
    __bf16* pro2_bf = (__bf16*)ws;                 ws += (size_t)4 * 128 * 128 * 2;
    __bf16* Xc   = (__bf16*)ws;                    ws += (size_t)8192 * 128 * 2;
    __bf16* preb = (__bf16*)ws;                    ws += (size_t)4 * 8192 * 128 * 2;
    float*  cur  = (float*)ws;                     ws += (size_t)8192 * 128 * 4;
    __bf16* Atb  = (__bf16*)ws;                    ws += (size_t)8192 * 1024 * 2;

    prep_all<<<2192, 256, 0, stream>>>(
        cur_qkv_w, cur_qkv_b, pre_qkv_w, pre_qkv_b, alpha, Wq, bq,
        proj_w, Wp_bf, 4 * 128 * 1024,
        ffn_w, Wf_bf, 4 * 128 * 128,
        pro1_w, pro1_bf, 128 * 128,
        pro2_w, pro2_bf, 4 * 128 * 128);
    lin_all<<<640, 256, 0, stream>>>(Hpre, pro2_bf, pro2_b, ln_pre_s, ln_pre_b,
                                     preb, seq, pro1_bf, pro1_b,
                                     ln_cur_s, ln_cur_b, cur, Xc);

    for (int l = 0; l < 4; ++l) {
        qkv_attn<<<1024, 256, 0, stream>>>(
            Xc, preb + (size_t)l * 8192 * 128,
            Wq + (size_t)l * 3072 * 256, bq + l * 3072,
            bn1_s + l * 128, bn1_b + l * 128, Atb);
        float* outp = (l == 3) ? (float*)d_out : cur;
        proj_ffn_mfma<<<512, 256, 0, stream>>>(Atb,
                                               Wp_bf + (size_t)l * 128 * 1024,
                                               proj_b + l * 128,
                                               bn2_s + l * 128, bn2_b + l * 128,
                                               ln_o_s + l * 128, ln_o_b + l * 128,
                                               Wf_bf + (size_t)l * 16384,
                                               ffn_b + l * 128,
                                               cur, outp, (l == 3) ? nullptr : Xc);
    }
}